// Round 14
// baseline (85.486 us; speedup 1.0000x reference)
//
#include <hip/hip_runtime.h>
#include <math.h>

// Tropical min-max matmul: out[b,o] = min_i max(x[b,i], w[i,o])
// B=1024, I=512, O=512, fp32.
//
// Round 14 = R13 architecture with the LDS pipe rebalanced. R13's 2x4
// thread tile needed 4 ds_read_b128 per 32 updates -> LDS 10.2us vs VALU
// 5.1us per CU (2:1, LDS-bound). LDS insts/update = 1/(4*rows): going to
// 4 rows halves LDS demand. Design:
//  - SINGLE dispatch, no workspace. Grid 256 (32x64 tile), 512 threads =
//    FOUR 128-thread k-groups (k-quarters of 128), thread tile 4x4.
//  - Per wave per k4: 4 wf b128 (48 LDS cyc) vs 96 VALU insts (192
//    SIMD-cyc at 2 waves/SIMD) -> LDS 5.1us == VALU 5.1us, balanced.
//  - w in LDS (reg-prefetched 32-k slabs, per-group); x direct from
//    global (4 unique 16B addrs per inst = TA broadcast, L1-hot).
//  - Combine: groups 1-3 write 16-float acc to wsh-reused scratch
//    (stride 20 floats -> <=2-way banks), group 0 min-combines + stores.
//  - min3 fusion: 1.5 VALU inst/update.

#define WSTR 68   // 17-quad row stride for w slabs

__device__ __forceinline__ float4 vmax4(float s, float4 v) {
    return make_float4(fmaxf(s, v.x), fmaxf(s, v.y), fmaxf(s, v.z), fmaxf(s, v.w));
}
__device__ __forceinline__ float4 vmin3(float4 a, float4 b, float4 c) {
    // fmin(fmin(a,b),c) -> v_min3_f32
    return make_float4(fminf(fminf(a.x, b.x), c.x),
                       fminf(fminf(a.y, b.y), c.y),
                       fminf(fminf(a.z, b.z), c.z),
                       fminf(fminf(a.w, b.w), c.w));
}
__device__ __forceinline__ float4 vmin2(float4 a, float4 b) {
    return make_float4(fminf(a.x, b.x), fminf(a.y, b.y),
                       fminf(a.z, b.z), fminf(a.w, b.w));
}

__global__ __launch_bounds__(512) void minmax_one(
    const float* __restrict__ x,    // [1024, 512]
    const float* __restrict__ w,    // [512, 512]
    float* __restrict__ out)        // [1024, 512]
{
    __shared__ float wsh[4][32 * WSTR];   // 34816 B; reused as combine scratch

    const int t  = threadIdx.x;     // 0..511
    const int g  = t >> 7;          // k-group 0..3: k in [g*128, g*128+128)
    const int t2 = t & 127;
    const int tx = t2 & 15;         // col quad: cols tx*4..+3
    const int ty = t2 >> 4;         // 0..7: rows ty+8r, r=0..3

    const int o0 = blockIdx.x * 64;
    const int r0 = blockIdx.y * 32;
    const int kg = g * 128;

    float4 acc[4];
#pragma unroll
    for (int r = 0; r < 4; ++r)
        acc[r] = make_float4(INFINITY, INFINITY, INFINITY, INFINITY);

    const float* xr[4];
#pragma unroll
    for (int r = 0; r < 4; ++r)
        xr[r] = x + (size_t)(r0 + ty + 8 * r) * 512 + kg;

    // w staging: 4 float4/thread per 32k-slab. f=i*128+t2: k=f>>4, c4=(f&15)*4
    float4 wp[4];
#pragma unroll
    for (int i = 0; i < 4; ++i) {
        const int f = i * 128 + t2;
        wp[i] = *(const float4*)(w + (size_t)(kg + (f >> 4)) * 512 + o0 + (f & 15) * 4);
    }

    for (int s = 0; s < 4; ++s) {
        __syncthreads();   // previous slab's LDS reads complete
#pragma unroll
        for (int i = 0; i < 4; ++i) {
            const int f = i * 128 + t2;
            *(float4*)(&wsh[g][(f >> 4) * WSTR + (f & 15) * 4]) = wp[i];
        }
        __syncthreads();
        if (s < 3) {
            const int kb = kg + (s + 1) * 32;
#pragma unroll
            for (int i = 0; i < 4; ++i) {
                const int f = i * 128 + t2;
                wp[i] = *(const float4*)(w + (size_t)(kb + (f >> 4)) * 512 + o0 + (f & 15) * 4);
            }
        }

        const int ks = s * 32;
#pragma unroll
        for (int k4 = 0; k4 < 8; ++k4) {
            float4 xf[4];
#pragma unroll
            for (int r = 0; r < 4; ++r)
                xf[r] = *(const float4*)(xr[r] + ks + 4 * k4);   // global, L1 broadcast
            float4 wf[4];
#pragma unroll
            for (int j = 0; j < 4; ++j)
                wf[j] = *(const float4*)(&wsh[g][(4 * k4 + j) * WSTR + tx * 4]);
#pragma unroll
            for (int r = 0; r < 4; ++r) {
                float4 a = acc[r];
                a = vmin3(a, vmax4(xf[r].x, wf[0]), vmax4(xf[r].y, wf[1]));
                a = vmin3(a, vmax4(xf[r].z, wf[2]), vmax4(xf[r].w, wf[3]));
                acc[r] = a;
            }
        }
    }

    // ---- cross-group combine: reuse wsh as scratch ----
    // groups 1..3 store 16 floats at stride 20 (5 quads, <=2-way banks):
    // 384 threads * 20 = 7680 floats <= 8704 available.
    float* scr = (float*)wsh;
    __syncthreads();   // all groups done reading their slabs
    if (g != 0) {
        float* sp = scr + ((g - 1) * 128 + t2) * 20;
#pragma unroll
        for (int r = 0; r < 4; ++r)
            *(float4*)(sp + 4 * r) = acc[r];
    }
    __syncthreads();
    if (g == 0) {
#pragma unroll
        for (int gg = 0; gg < 3; ++gg) {
            const float* sp = scr + (gg * 128 + t2) * 20;
#pragma unroll
            for (int r = 0; r < 4; ++r)
                acc[r] = vmin2(acc[r], *(const float4*)(sp + 4 * r));
        }
#pragma unroll
        for (int r = 0; r < 4; ++r)
            *(float4*)(out + (size_t)(r0 + ty + 8 * r) * 512 + o0 + tx * 4) = acc[r];
    }
}

extern "C" void kernel_launch(void* const* d_in, const int* in_sizes, int n_in,
                              void* d_out, int out_size, void* d_ws, size_t ws_size,
                              hipStream_t stream) {
    const float* x = (const float*)d_in[0];   // [1024, 512]
    const float* w = (const float*)d_in[1];   // [512, 512]
    float* out = (float*)d_out;               // [1024, 512]

    minmax_one<<<dim3(8, 32), 512, 0, stream>>>(x, w, out);
}

// Round 15
// 78.996 us; speedup vs baseline: 1.0822x; 1.0822x over previous
//
#include <hip/hip_runtime.h>
#include <math.h>

// Tropical min-max matmul: out[b,o] = min_i max(x[b,i], w[i,o])
// B=1024, I=512, O=512, fp32.
//
// Round 15 = Round 13 (best measured: 79.4 total) + ONE change: w slabs
// are double-buffered, so each 32-k slab costs ONE barrier (8 total vs
// R13's 16) and next-slab global loads overlap compute instead of being
// fenced between two barriers.
//  - SINGLE dispatch, no workspace. Grid 256 (32x64 tile), 512 threads =
//    two 256-thread k-groups (k-halves), 8 waves/CU, thread tile 2x4.
//  - w in LDS per-group (17408B x2 buffers); x direct from global
//    (4 unique 16B addrs/wave = TA broadcast, L1-hot).
//  - min3 fusion 1.5 inst/update; intra-block combine via LDS scratch.
//  - R14's 4x4/four-group rebalance regressed (85.5): x-register
//    pressure + combine tail; reverted.

#define WSTR 68   // 17-quad row stride for w slabs

__device__ __forceinline__ float4 vmax4(float s, float4 v) {
    return make_float4(fmaxf(s, v.x), fmaxf(s, v.y), fmaxf(s, v.z), fmaxf(s, v.w));
}
__device__ __forceinline__ float4 vmin3(float4 a, float4 b, float4 c) {
    // fmin(fmin(a,b),c) -> v_min3_f32
    return make_float4(fminf(fminf(a.x, b.x), c.x),
                       fminf(fminf(a.y, b.y), c.y),
                       fminf(fminf(a.z, b.z), c.z),
                       fminf(fminf(a.w, b.w), c.w));
}
__device__ __forceinline__ float4 vmin2(float4 a, float4 b) {
    return make_float4(fminf(a.x, b.x), fminf(a.y, b.y),
                       fminf(a.z, b.z), fminf(a.w, b.w));
}

__global__ __launch_bounds__(512, 1) void minmax_one(
    const float* __restrict__ x,    // [1024, 512]
    const float* __restrict__ w,    // [512, 512]
    float* __restrict__ out)        // [1024, 512]
{
    __shared__ float wsh[2][2][32 * WSTR];   // [group][buf], 34816 B
    __shared__ float scr[256 * 12];          // combine scratch, 12288 B

    const int t  = threadIdx.x;     // 0..511
    const int g  = t >> 8;          // k-group: g0 -> k in [0,256), g1 -> [256,512)
    const int t2 = t & 255;
    const int tx = t2 & 15;         // cols tx*4..+3
    const int ty = t2 >> 4;         // rows ty and ty+16

    const int o0 = blockIdx.x * 64;
    const int r0 = blockIdx.y * 32;
    const int kg = g * 256;

    // w staging map: 2 float4/thread per 32-k slab (rows wk, wk+16)
    const int wk = t2 >> 4;         // 0..15
    const int wc = (t2 & 15) * 4;   // 0..60

    const float* xr0 = x + (size_t)(r0 + ty) * 512 + kg;
    const float* xr1 = x + (size_t)(r0 + ty + 16) * 512 + kg;

    float4 acc0 = make_float4(INFINITY, INFINITY, INFINITY, INFINITY);
    float4 acc1 = make_float4(INFINITY, INFINITY, INFINITY, INFINITY);

    // stage slab 0 into buffer 0
    {
        const float4 a = *(const float4*)(w + (size_t)(kg + wk) * 512 + o0 + wc);
        const float4 b = *(const float4*)(w + (size_t)(kg + wk + 16) * 512 + o0 + wc);
        *(float4*)(&wsh[g][0][wk * WSTR + wc])        = a;
        *(float4*)(&wsh[g][0][(wk + 16) * WSTR + wc]) = b;
    }
    __syncthreads();

    for (int s = 0; s < 8; ++s) {
        const int cur = s & 1;

        // issue next slab's global loads before compute (overlap)
        float4 wpre0, wpre1;
        if (s < 7) {
            const int kb = kg + (s + 1) * 32;
            wpre0 = *(const float4*)(w + (size_t)(kb + wk) * 512 + o0 + wc);
            wpre1 = *(const float4*)(w + (size_t)(kb + wk + 16) * 512 + o0 + wc);
        }

        const int ks = s * 32;
        const float* wb = wsh[g][cur];
#pragma unroll
        for (int k4 = 0; k4 < 8; ++k4) {
            // x from global: 4 unique addrs/wave (16-lane broadcast), L1-hot
            const float4 xf0 = *(const float4*)(xr0 + ks + 4 * k4);
            const float4 xf1 = *(const float4*)(xr1 + ks + 4 * k4);
            float4 wf[4];
#pragma unroll
            for (int j = 0; j < 4; ++j)
                wf[j] = *(const float4*)(&wb[(4 * k4 + j) * WSTR + tx * 4]);

            acc0 = vmin3(acc0, vmax4(xf0.x, wf[0]), vmax4(xf0.y, wf[1]));
            acc0 = vmin3(acc0, vmax4(xf0.z, wf[2]), vmax4(xf0.w, wf[3]));
            acc1 = vmin3(acc1, vmax4(xf1.x, wf[0]), vmax4(xf1.y, wf[1]));
            acc1 = vmin3(acc1, vmax4(xf1.z, wf[2]), vmax4(xf1.w, wf[3]));
        }

        // store next slab into the other buffer; one barrier per slab
        if (s < 7) {
            *(float4*)(&wsh[g][cur ^ 1][wk * WSTR + wc])        = wpre0;
            *(float4*)(&wsh[g][cur ^ 1][(wk + 16) * WSTR + wc]) = wpre1;
        }
        __syncthreads();
    }

    // ---- cross-group combine (intra-block, no fences) ----
    if (g == 1) {
        *(float4*)(&scr[t2 * 12])     = acc0;
        *(float4*)(&scr[t2 * 12 + 4]) = acc1;
    }
    __syncthreads();
    if (g == 0) {
        const float4 p0 = *(const float4*)(&scr[t2 * 12]);
        const float4 p1 = *(const float4*)(&scr[t2 * 12 + 4]);
        const float4 out0 = vmin2(acc0, p0);
        const float4 out1 = vmin2(acc1, p1);
        *(float4*)(out + (size_t)(r0 + ty) * 512 + o0 + tx * 4)      = out0;
        *(float4*)(out + (size_t)(r0 + ty + 16) * 512 + o0 + tx * 4) = out1;
    }
}

extern "C" void kernel_launch(void* const* d_in, const int* in_sizes, int n_in,
                              void* d_out, int out_size, void* d_ws, size_t ws_size,
                              hipStream_t stream) {
    const float* x = (const float*)d_in[0];   // [1024, 512]
    const float* w = (const float*)d_in[1];   // [512, 512]
    float* out = (float*)d_out;               // [1024, 512]

    minmax_one<<<dim3(8, 32), 512, 0, stream>>>(x, w, out);
}